// Round 5
// baseline (124.786 us; speedup 1.0000x reference)
//
#include <hip/hip_runtime.h>
#include <math.h>

#define NC     1000
#define DIM    2048
#define NBATCH 8192
#define NUNITS 4000     // class * column-quarter
#define QCOLS  512
#define NPERS  2048     // persistent blocks (8 per CU)

typedef float  f32x2 __attribute__((ext_vector_type(2)));
typedef int    i32x4 __attribute__((ext_vector_type(4)));

// Persistent blocks, dynamic work queue. Unit u: class c=u>>2, quarter q=u&3.
// 256 threads; thread t owns cols q*512 + [2t, 2t+2).
// ws: [0]=refill counter (int), [1]=done counter (int), [2]=loss accum (float).
__global__ __launch_bounds__(256) void k_main(
        const int*   __restrict__ y,
        const float* __restrict__ feat,
        const float* __restrict__ centers,
        float* __restrict__ grad_out,     // d_out + 1 (4B-aligned only)
        int*   __restrict__ ws_i,
        float* __restrict__ out) {
    const int t = threadIdx.x;

    __shared__ unsigned short sidx[NBATCH];   // 16 KB worst case
    __shared__ int scur;
    __shared__ int s_u;
    __shared__ float red[4];

    float block_lsum = 0.f;
    int u = blockIdx.x;   // static first unit, no atomic burst at t=0

    for (;;) {
        if (u >= NUNITS) break;
        const int c   = u >> 2;
        const int col = (u & 3) * QCOLS + 2 * t;

        const f32x2 cen = *(const f32x2*)(centers + (size_t)c * DIM + col);

        if (t == 0) scur = 0;
        __syncthreads();                       // scur ready; sidx safe to rewrite

        // scan y (L2-resident): 8 int4 per thread
        const i32x4* y4 = (const i32x4*)y;
        for (int j = t; j < NBATCH / 4; j += 256) {
            i32x4 v = y4[j];
            int base = 4 * j;
            if (v.x == c) sidx[atomicAdd(&scur, 1)] = (unsigned short)(base + 0);
            if (v.y == c) sidx[atomicAdd(&scur, 1)] = (unsigned short)(base + 1);
            if (v.z == c) sidx[atomicAdd(&scur, 1)] = (unsigned short)(base + 2);
            if (v.w == c) sidx[atomicAdd(&scur, 1)] = (unsigned short)(base + 3);
        }
        __syncthreads();
        const int n = scur;

        f32x2 acc = (f32x2)(0.f);
        float lsum = 0.f;

        int r = 0;
        for (; r + 4 <= n; r += 4) {
            int i0 = sidx[r], i1 = sidx[r+1], i2 = sidx[r+2], i3 = sidx[r+3];
            f32x2 v0 = __builtin_nontemporal_load((const f32x2*)(feat + (size_t)i0 * DIM + col));
            f32x2 v1 = __builtin_nontemporal_load((const f32x2*)(feat + (size_t)i1 * DIM + col));
            f32x2 v2 = __builtin_nontemporal_load((const f32x2*)(feat + (size_t)i2 * DIM + col));
            f32x2 v3 = __builtin_nontemporal_load((const f32x2*)(feat + (size_t)i3 * DIM + col));
            acc += v0 + v1 + v2 + v3;
            f32x2 d0 = v0 - cen, d1 = v1 - cen, d2 = v2 - cen, d3 = v3 - cen;
            f32x2 sq = d0 * d0 + d1 * d1 + d2 * d2 + d3 * d3;
            lsum += sq.x + sq.y;
        }
        for (; r < n; ++r) {
            f32x2 v0 = __builtin_nontemporal_load((const f32x2*)(feat + (size_t)sidx[r] * DIM + col));
            acc += v0;
            f32x2 d0 = v0 - cen;
            lsum += d0.x * d0.x + d0.y * d0.y;
        }

        // grad = coeff * (centers - mean); zero when n == 0
        f32x2 g = (f32x2)(0.f);
        if (n > 0) {
            float fn = (float)n;
            float coeff = fn / (1.0f + fn);
            g = coeff * (cen - acc * (1.0f / fn));
        }
        float* go = grad_out + (size_t)c * DIM + col;   // odd base -> scalar stores
        __builtin_nontemporal_store(g.x, go + 0);
        __builtin_nontemporal_store(g.y, go + 1);

        // block-reduce lsum into block_lsum (thread 0)
        for (int sh = 32; sh > 0; sh >>= 1) lsum += __shfl_down(lsum, sh);
        if ((t & 63) == 0) red[t >> 6] = lsum;
        __syncthreads();
        if (t == 0) block_lsum += red[0] + red[1] + red[2] + red[3];

        // grab next unit
        if (t == 0) s_u = NPERS + atomicAdd(&ws_i[0], 1);
        __syncthreads();                       // also protects sidx/red reuse
        u = s_u;
    }

    // fenced last-block loss finalize
    if (t == 0) {
        float* loss_acc = (float*)&ws_i[2];
        atomicAdd(loss_acc, block_lsum);
        __threadfence();
        int old = atomicAdd(&ws_i[1], 1);
        if (old == NPERS - 1) {
            float tot = atomicAdd(loss_acc, 0.0f);   // coherent read
            out[0] = 0.5f * sqrtf(tot) / (float)NBATCH;
        }
    }
}

extern "C" void kernel_launch(void* const* d_in, const int* in_sizes, int n_in,
                              void* d_out, int out_size, void* d_ws, size_t ws_size,
                              hipStream_t stream) {
    const int*   y       = (const int*)d_in[0];
    const float* feat    = (const float*)d_in[1];
    const float* centers = (const float*)d_in[2];
    float* out = (float*)d_out;
    int* ws_i = (int*)d_ws;

    hipMemsetAsync(d_ws, 0, 12, stream);   // queue, done, loss accum
    k_main<<<NPERS, 256, 0, stream>>>(y, feat, centers, out + 1, ws_i, out);
}

// Round 6
// 92.202 us; speedup vs baseline: 1.3534x; 1.3534x over previous
//
#include <hip/hip_runtime.h>
#include <math.h>

#define NC     1000
#define NBLK   2000     // 2 column-half blocks per class
#define DIM    2048
#define HALF   1024
#define NBATCH 8192

typedef float f32x4 __attribute__((ext_vector_type(4)));
typedef int   i32x4 __attribute__((ext_vector_type(4)));

// ws layout (bytes):
// [0, 32768)      rowidx int[8192]  (row indices grouped by class)
// [32768, 36864)  offsets int[1024]
// [36864, 40960)  counts  int[1024]
// [40960, 41024)  loss accumulator (float, own cacheline)
// [41024, 41088)  done counter (int, own cacheline)

// Single block: counting-sort the 8192 labels by class.
// Also zero-inits the loss/done cells (stream order makes them visible to k_gather).
__global__ __launch_bounds__(1024) void k_sort(
        const int* __restrict__ y,
        int* __restrict__ rowidx, int* __restrict__ offsets, int* __restrict__ counts,
        float* __restrict__ loss_acc, int* __restrict__ done) {
    __shared__ int hist[1024];
    __shared__ int excl[1024];
    __shared__ int lcur[1024];
    const int t = threadIdx.x;

    hist[t] = 0;
    __syncthreads();

    i32x4 v0 = ((const i32x4*)y)[t];
    i32x4 v1 = ((const i32x4*)y)[t + 1024];
    atomicAdd(&hist[v0.x], 1); atomicAdd(&hist[v0.y], 1);
    atomicAdd(&hist[v0.z], 1); atomicAdd(&hist[v0.w], 1);
    atomicAdd(&hist[v1.x], 1); atomicAdd(&hist[v1.y], 1);
    atomicAdd(&hist[v1.z], 1); atomicAdd(&hist[v1.w], 1);
    __syncthreads();

    // inclusive Hillis-Steele scan over 1024 bins
    int val = hist[t];
    excl[t] = val;
    __syncthreads();
    for (int off = 1; off < 1024; off <<= 1) {
        int add = (t >= off) ? excl[t - off] : 0;
        __syncthreads();
        excl[t] += add;
        __syncthreads();
    }
    int ex = excl[t] - val;           // exclusive prefix
    lcur[t] = ex;
    offsets[t] = ex;
    counts[t] = val;
    if (t == 0) { *loss_acc = 0.0f; *done = 0; }
    __syncthreads();

    int b0 = 4 * t, b1 = 4 * (t + 1024);
    rowidx[atomicAdd(&lcur[v0.x], 1)] = b0 + 0;
    rowidx[atomicAdd(&lcur[v0.y], 1)] = b0 + 1;
    rowidx[atomicAdd(&lcur[v0.z], 1)] = b0 + 2;
    rowidx[atomicAdd(&lcur[v0.w], 1)] = b0 + 3;
    rowidx[atomicAdd(&lcur[v1.x], 1)] = b1 + 0;
    rowidx[atomicAdd(&lcur[v1.y], 1)] = b1 + 1;
    rowidx[atomicAdd(&lcur[v1.z], 1)] = b1 + 2;
    rowidx[atomicAdd(&lcur[v1.w], 1)] = b1 + 3;
}

// Grid: 2000 blocks = 1000 classes x 2 column halves; 256 threads.
// Thread t of block (c,h) owns cols h*1024 + [4t, 4t+4).
__global__ __launch_bounds__(256) void k_gather(
        const float* __restrict__ feat,
        const float* __restrict__ centers,
        const int*   __restrict__ rowidx,
        const int*   __restrict__ offsets,
        const int*   __restrict__ counts,
        float* __restrict__ grad_out,     // d_out + 1 (4B-aligned only)
        float* __restrict__ loss_acc,
        int*   __restrict__ done,
        float* __restrict__ out) {
    const int c = blockIdx.x >> 1;
    const int h = blockIdx.x & 1;
    const int t = threadIdx.x;
    const int col = h * HALF + t * 4;

    const f32x4 cen = *(const f32x4*)(centers + (size_t)c * DIM + col);
    const int n   = counts[c];
    const int off = offsets[c];
    const int* rix = rowidx + off;

    f32x4 acc = (f32x4)(0.f);
    f32x4 sq  = (f32x4)(0.f);

    int r = 0;
    for (; r + 8 <= n; r += 8) {
        int i0 = rix[r+0], i1 = rix[r+1], i2 = rix[r+2], i3 = rix[r+3];
        int i4 = rix[r+4], i5 = rix[r+5], i6 = rix[r+6], i7 = rix[r+7];
        f32x4 v0 = *(const f32x4*)(feat + (size_t)i0 * DIM + col);
        f32x4 v1 = *(const f32x4*)(feat + (size_t)i1 * DIM + col);
        f32x4 v2 = *(const f32x4*)(feat + (size_t)i2 * DIM + col);
        f32x4 v3 = *(const f32x4*)(feat + (size_t)i3 * DIM + col);
        f32x4 v4 = *(const f32x4*)(feat + (size_t)i4 * DIM + col);
        f32x4 v5 = *(const f32x4*)(feat + (size_t)i5 * DIM + col);
        f32x4 v6 = *(const f32x4*)(feat + (size_t)i6 * DIM + col);
        f32x4 v7 = *(const f32x4*)(feat + (size_t)i7 * DIM + col);
        acc += v0 + v1 + v2 + v3 + v4 + v5 + v6 + v7;
        f32x4 d0 = v0 - cen, d1 = v1 - cen, d2 = v2 - cen, d3 = v3 - cen;
        f32x4 d4 = v4 - cen, d5 = v5 - cen, d6 = v6 - cen, d7 = v7 - cen;
        sq += d0*d0 + d1*d1 + d2*d2 + d3*d3 + d4*d4 + d5*d5 + d6*d6 + d7*d7;
    }
    for (; r < n; ++r) {
        f32x4 v0 = *(const f32x4*)(feat + (size_t)rix[r] * DIM + col);
        acc += v0;
        f32x4 d0 = v0 - cen;
        sq += d0 * d0;
    }
    float lsum = sq.x + sq.y + sq.z + sq.w;

    // grad = coeff * (centers - mean); zero when n == 0
    f32x4 g = (f32x4)(0.f);
    if (n > 0) {
        float fn = (float)n;
        float coeff = fn / (1.0f + fn);
        g = coeff * (cen - acc * (1.0f / fn));
    }
    float* go = grad_out + (size_t)c * DIM + col;   // odd base -> scalar stores
    go[0] = g.x; go[1] = g.y; go[2] = g.z; go[3] = g.w;

    // block-reduce lsum (4 waves)
    for (int sh = 32; sh > 0; sh >>= 1) lsum += __shfl_down(lsum, sh);
    __shared__ float red[4];
    if ((t & 63) == 0) red[t >> 6] = lsum;
    __syncthreads();

    // fenced last-block loss finalize
    if (t == 0) {
        atomicAdd(loss_acc, red[0] + red[1] + red[2] + red[3]);
        __threadfence();
        int old = atomicAdd(done, 1);
        if (old == NBLK - 1) {
            float tot = atomicAdd(loss_acc, 0.0f);   // coherent read of final sum
            out[0] = 0.5f * sqrtf(tot) / (float)NBATCH;
        }
    }
}

extern "C" void kernel_launch(void* const* d_in, const int* in_sizes, int n_in,
                              void* d_out, int out_size, void* d_ws, size_t ws_size,
                              hipStream_t stream) {
    const int*   y       = (const int*)d_in[0];
    const float* feat    = (const float*)d_in[1];
    const float* centers = (const float*)d_in[2];
    float* out = (float*)d_out;

    char* ws = (char*)d_ws;
    int*   rowidx   = (int*)(ws);
    int*   offsets  = (int*)(ws + 32768);
    int*   counts   = (int*)(ws + 36864);
    float* loss_acc = (float*)(ws + 40960);
    int*   done     = (int*)(ws + 41024);

    k_sort  <<<1, 1024, 0, stream>>>(y, rowidx, offsets, counts, loss_acc, done);
    k_gather<<<NBLK, 256, 0, stream>>>(feat, centers, rowidx, offsets, counts,
                                       out + 1, loss_acc, done, out);
}

// Round 7
// 28.768 us; speedup vs baseline: 4.3377x; 3.2051x over previous
//
#include <hip/hip_runtime.h>
#include <math.h>

#define NC     1000
#define NBLK   2000     // 2 column-half blocks per class
#define DIM    2048
#define HALF   1024
#define NBATCH 8192

typedef float f32x4 __attribute__((ext_vector_type(4)));
typedef int   i32x4 __attribute__((ext_vector_type(4)));

// ws layout (bytes):
// [0, 32768)      rowidx int[8192]  (row indices grouped by class)
// [32768, 36864)  offsets int[1024]
// [36864, 40960)  counts  int[1024]
// [40960, 48960)  partials float[2000]

// Single block: counting-sort the 8192 labels by class (shuffle-scan, 4 barriers).
__global__ __launch_bounds__(1024) void k_sort(
        const int* __restrict__ y,
        int* __restrict__ rowidx, int* __restrict__ offsets, int* __restrict__ counts) {
    __shared__ int hist[1024];
    __shared__ int warpsum[16];
    __shared__ int lcur[1024];
    const int t = threadIdx.x;
    const int lane = t & 63;

    hist[t] = 0;
    __syncthreads();

    i32x4 v0 = ((const i32x4*)y)[t];
    i32x4 v1 = ((const i32x4*)y)[t + 1024];
    atomicAdd(&hist[v0.x], 1); atomicAdd(&hist[v0.y], 1);
    atomicAdd(&hist[v0.z], 1); atomicAdd(&hist[v0.w], 1);
    atomicAdd(&hist[v1.x], 1); atomicAdd(&hist[v1.y], 1);
    atomicAdd(&hist[v1.z], 1); atomicAdd(&hist[v1.w], 1);
    __syncthreads();

    const int val = hist[t];
    int v = val;
    // inclusive scan within each 64-lane wave
    for (int d = 1; d < 64; d <<= 1) {
        int x = __shfl_up(v, d);
        if (lane >= d) v += x;
    }
    if (lane == 63) warpsum[t >> 6] = v;
    __syncthreads();
    if (t < 16) {
        int s = warpsum[t];
        for (int d = 1; d < 16; d <<= 1) {
            int x = __shfl_up(s, d);
            if (t >= d) s += x;
        }
        warpsum[t] = s;   // inclusive over warp sums
    }
    __syncthreads();
    const int base = (t >= 64) ? warpsum[(t >> 6) - 1] : 0;
    const int ex = v + base - val;   // exclusive prefix
    offsets[t] = ex;
    counts[t] = val;
    lcur[t] = ex;
    __syncthreads();

    int b0 = 4 * t, b1 = 4 * (t + 1024);
    rowidx[atomicAdd(&lcur[v0.x], 1)] = b0 + 0;
    rowidx[atomicAdd(&lcur[v0.y], 1)] = b0 + 1;
    rowidx[atomicAdd(&lcur[v0.z], 1)] = b0 + 2;
    rowidx[atomicAdd(&lcur[v0.w], 1)] = b0 + 3;
    rowidx[atomicAdd(&lcur[v1.x], 1)] = b1 + 0;
    rowidx[atomicAdd(&lcur[v1.y], 1)] = b1 + 1;
    rowidx[atomicAdd(&lcur[v1.z], 1)] = b1 + 2;
    rowidx[atomicAdd(&lcur[v1.w], 1)] = b1 + 3;
}

// Grid: 2000 blocks = 1000 classes x 2 column halves; 256 threads.
// Thread t of block (c,h) owns cols h*1024 + [4t, 4t+4).
__global__ __launch_bounds__(256) void k_gather(
        const float* __restrict__ feat,
        const float* __restrict__ centers,
        const int*   __restrict__ rowidx,
        const int*   __restrict__ offsets,
        const int*   __restrict__ counts,
        float* __restrict__ grad_out,     // d_out + 1 (4B-aligned only)
        float* __restrict__ partials) {
    const int c = blockIdx.x >> 1;
    const int h = blockIdx.x & 1;
    const int t = threadIdx.x;
    const int col = h * HALF + t * 4;

    const f32x4 cen = *(const f32x4*)(centers + (size_t)c * DIM + col);
    const int n   = counts[c];
    const int off = offsets[c];
    const int* rix = rowidx + off;

    f32x4 acc = (f32x4)(0.f);
    f32x4 sq  = (f32x4)(0.f);

    int r = 0;
    for (; r + 8 <= n; r += 8) {
        int i0 = rix[r+0], i1 = rix[r+1], i2 = rix[r+2], i3 = rix[r+3];
        int i4 = rix[r+4], i5 = rix[r+5], i6 = rix[r+6], i7 = rix[r+7];
        f32x4 v0 = __builtin_nontemporal_load((const f32x4*)(feat + (size_t)i0 * DIM + col));
        f32x4 v1 = __builtin_nontemporal_load((const f32x4*)(feat + (size_t)i1 * DIM + col));
        f32x4 v2 = __builtin_nontemporal_load((const f32x4*)(feat + (size_t)i2 * DIM + col));
        f32x4 v3 = __builtin_nontemporal_load((const f32x4*)(feat + (size_t)i3 * DIM + col));
        f32x4 v4 = __builtin_nontemporal_load((const f32x4*)(feat + (size_t)i4 * DIM + col));
        f32x4 v5 = __builtin_nontemporal_load((const f32x4*)(feat + (size_t)i5 * DIM + col));
        f32x4 v6 = __builtin_nontemporal_load((const f32x4*)(feat + (size_t)i6 * DIM + col));
        f32x4 v7 = __builtin_nontemporal_load((const f32x4*)(feat + (size_t)i7 * DIM + col));
        acc += v0 + v1 + v2 + v3 + v4 + v5 + v6 + v7;
        f32x4 d0 = v0 - cen, d1 = v1 - cen, d2 = v2 - cen, d3 = v3 - cen;
        f32x4 d4 = v4 - cen, d5 = v5 - cen, d6 = v6 - cen, d7 = v7 - cen;
        sq += d0*d0 + d1*d1 + d2*d2 + d3*d3 + d4*d4 + d5*d5 + d6*d6 + d7*d7;
    }
    for (; r < n; ++r) {
        f32x4 v0 = __builtin_nontemporal_load((const f32x4*)(feat + (size_t)rix[r] * DIM + col));
        acc += v0;
        f32x4 d0 = v0 - cen;
        sq += d0 * d0;
    }
    float lsum = sq.x + sq.y + sq.z + sq.w;

    // grad = coeff * (centers - mean); zero when n == 0
    f32x4 g = (f32x4)(0.f);
    if (n > 0) {
        float fn = (float)n;
        float coeff = fn / (1.0f + fn);
        g = coeff * (cen - acc * (1.0f / fn));
    }
    float* go = grad_out + (size_t)c * DIM + col;   // odd base -> scalar NT stores
    __builtin_nontemporal_store(g.x, go + 0);
    __builtin_nontemporal_store(g.y, go + 1);
    __builtin_nontemporal_store(g.z, go + 2);
    __builtin_nontemporal_store(g.w, go + 3);

    // block-reduce lsum (4 waves) -> per-block partial (NO atomics, NO fence)
    for (int sh = 32; sh > 0; sh >>= 1) lsum += __shfl_down(lsum, sh);
    __shared__ float red[4];
    if ((t & 63) == 0) red[t >> 6] = lsum;
    __syncthreads();
    if (t == 0) partials[blockIdx.x] = red[0] + red[1] + red[2] + red[3];
}

__global__ void k_loss(const float* __restrict__ partials, float* __restrict__ out) {
    __shared__ float s[256];
    int t = threadIdx.x;
    float v = 0.f;
    for (int i = t; i < NBLK; i += 256) v += partials[i];
    s[t] = v;
    __syncthreads();
    for (int off = 128; off > 0; off >>= 1) {
        if (t < off) s[t] += s[t + off];
        __syncthreads();
    }
    if (t == 0) out[0] = 0.5f * sqrtf(s[0]) / (float)NBATCH;
}

extern "C" void kernel_launch(void* const* d_in, const int* in_sizes, int n_in,
                              void* d_out, int out_size, void* d_ws, size_t ws_size,
                              hipStream_t stream) {
    const int*   y       = (const int*)d_in[0];
    const float* feat    = (const float*)d_in[1];
    const float* centers = (const float*)d_in[2];
    float* out = (float*)d_out;

    char* ws = (char*)d_ws;
    int*   rowidx   = (int*)(ws);
    int*   offsets  = (int*)(ws + 32768);
    int*   counts   = (int*)(ws + 36864);
    float* partials = (float*)(ws + 40960);

    k_sort  <<<1, 1024, 0, stream>>>(y, rowidx, offsets, counts);
    k_gather<<<NBLK, 256, 0, stream>>>(feat, centers, rowidx, offsets, counts,
                                       out + 1, partials);
    k_loss  <<<1, 256, 0, stream>>>(partials, out);
}

// Round 8
// 26.279 us; speedup vs baseline: 4.7485x; 1.0947x over previous
//
#include <hip/hip_runtime.h>
#include <math.h>

#define NC     1000
#define NBLK   2000     // 2 column-half blocks per class
#define DIM    2048
#define HALF   1024
#define NBATCH 8192
#define MAXN   1024     // sidx capacity; true max class count ~25 (Poisson(8.2))

typedef float f32x4 __attribute__((ext_vector_type(4)));
typedef int   i32x4 __attribute__((ext_vector_type(4)));

// Grid: 2000 blocks = 1000 classes x 2 column halves; 256 threads.
// Thread t of block (c,h) owns cols h*1024 + [4t, 4t+4).
// 24 KB dynamic LDS caps residency at 6 blocks/CU (capacity 1536 < 2000)
// so the 464 tail blocks are dispatched dynamically -> load balancing.
__global__ __launch_bounds__(256) void k_main(
        const int*   __restrict__ y,
        const float* __restrict__ feat,
        const float* __restrict__ centers,
        float* __restrict__ grad_out,     // d_out + 1 (4B-aligned only)
        float* __restrict__ partials) {   // [2000]
    extern __shared__ char lds_pad[];     // residency throttle (written never-taken)
    const int c = blockIdx.x >> 1;
    const int h = blockIdx.x & 1;
    const int t = threadIdx.x;
    const int col = h * HALF + t * 4;

    const f32x4 cen = *(const f32x4*)(centers + (size_t)c * DIM + col);

    __shared__ unsigned short sidx[MAXN];
    __shared__ int scur;
    if (t == 0) scur = 0;
    __syncthreads();

    // scan y (L2-resident): 8 int4 per thread
    const i32x4* y4 = (const i32x4*)y;
    for (int j = t; j < NBATCH / 4; j += 256) {
        i32x4 v = y4[j];
        int base = 4 * j;
        if (v.x == c) sidx[atomicAdd(&scur, 1) & (MAXN - 1)] = (unsigned short)(base + 0);
        if (v.y == c) sidx[atomicAdd(&scur, 1) & (MAXN - 1)] = (unsigned short)(base + 1);
        if (v.z == c) sidx[atomicAdd(&scur, 1) & (MAXN - 1)] = (unsigned short)(base + 2);
        if (v.w == c) sidx[atomicAdd(&scur, 1) & (MAXN - 1)] = (unsigned short)(base + 3);
    }
    __syncthreads();
    const int n = scur;
    if (n < 0) lds_pad[t] = 0;   // keep dynamic LDS alive; never taken

    f32x4 acc = (f32x4)(0.f);
    f32x4 sq  = (f32x4)(0.f);

    int r = 0;
    for (; r + 8 <= n; r += 8) {
        int i0 = sidx[r+0], i1 = sidx[r+1], i2 = sidx[r+2], i3 = sidx[r+3];
        int i4 = sidx[r+4], i5 = sidx[r+5], i6 = sidx[r+6], i7 = sidx[r+7];
        f32x4 v0 = __builtin_nontemporal_load((const f32x4*)(feat + (size_t)i0 * DIM + col));
        f32x4 v1 = __builtin_nontemporal_load((const f32x4*)(feat + (size_t)i1 * DIM + col));
        f32x4 v2 = __builtin_nontemporal_load((const f32x4*)(feat + (size_t)i2 * DIM + col));
        f32x4 v3 = __builtin_nontemporal_load((const f32x4*)(feat + (size_t)i3 * DIM + col));
        f32x4 v4 = __builtin_nontemporal_load((const f32x4*)(feat + (size_t)i4 * DIM + col));
        f32x4 v5 = __builtin_nontemporal_load((const f32x4*)(feat + (size_t)i5 * DIM + col));
        f32x4 v6 = __builtin_nontemporal_load((const f32x4*)(feat + (size_t)i6 * DIM + col));
        f32x4 v7 = __builtin_nontemporal_load((const f32x4*)(feat + (size_t)i7 * DIM + col));
        acc += v0 + v1 + v2 + v3 + v4 + v5 + v6 + v7;
        f32x4 d0 = v0 - cen, d1 = v1 - cen, d2 = v2 - cen, d3 = v3 - cen;
        f32x4 d4 = v4 - cen, d5 = v5 - cen, d6 = v6 - cen, d7 = v7 - cen;
        sq += d0*d0 + d1*d1 + d2*d2 + d3*d3 + d4*d4 + d5*d5 + d6*d6 + d7*d7;
    }
    for (; r < n; ++r) {
        f32x4 v0 = __builtin_nontemporal_load((const f32x4*)(feat + (size_t)sidx[r] * DIM + col));
        acc += v0;
        f32x4 d0 = v0 - cen;
        sq += d0 * d0;
    }
    float lsum = sq.x + sq.y + sq.z + sq.w;

    // grad = coeff * (centers - mean); zero when n == 0
    f32x4 g = (f32x4)(0.f);
    if (n > 0) {
        float fn = (float)n;
        float coeff = fn / (1.0f + fn);
        g = coeff * (cen - acc * (1.0f / fn));
    }
    float* go = grad_out + (size_t)c * DIM + col;   // odd base -> scalar NT stores
    __builtin_nontemporal_store(g.x, go + 0);
    __builtin_nontemporal_store(g.y, go + 1);
    __builtin_nontemporal_store(g.z, go + 2);
    __builtin_nontemporal_store(g.w, go + 3);

    // block-reduce lsum (4 waves) -> per-block partial
    for (int sh = 32; sh > 0; sh >>= 1) lsum += __shfl_down(lsum, sh);
    __shared__ float red[4];
    if ((t & 63) == 0) red[t >> 6] = lsum;
    __syncthreads();
    if (t == 0) partials[blockIdx.x] = red[0] + red[1] + red[2] + red[3];
}

__global__ void k_loss(const float* __restrict__ partials, float* __restrict__ out) {
    __shared__ float s[256];
    int t = threadIdx.x;
    float v = 0.f;
    for (int i = t; i < NBLK; i += 256) v += partials[i];
    s[t] = v;
    __syncthreads();
    for (int off = 128; off > 0; off >>= 1) {
        if (t < off) s[t] += s[t + off];
        __syncthreads();
    }
    if (t == 0) out[0] = 0.5f * sqrtf(s[0]) / (float)NBATCH;
}

extern "C" void kernel_launch(void* const* d_in, const int* in_sizes, int n_in,
                              void* d_out, int out_size, void* d_ws, size_t ws_size,
                              hipStream_t stream) {
    const int*   y       = (const int*)d_in[0];
    const float* feat    = (const float*)d_in[1];
    const float* centers = (const float*)d_in[2];
    float* out = (float*)d_out;
    float* partials = (float*)d_ws;   // 2000 floats, fully rewritten each call

    k_main<<<NBLK, 256, 24576, stream>>>(y, feat, centers, out + 1, partials);
    k_loss<<<1, 256, 0, stream>>>(partials, out);
}